// Round 1
// baseline (72.941 us; speedup 1.0000x reference)
//
#include <hip/hip_runtime.h>

#define B_   4
#define C_   64
#define H_   128
#define W_   128
#define KS   7
#define G_   4
#define GC_  16
#define KK   49
#define PAD  3
#define TH   16
#define TW   16
#define HW_  (H_ * W_)
#define HALO_H (TH + KS - 1)   // 22
#define HALO_W (TW + KS - 1)   // 22

__global__ __launch_bounds__(256, 4) void invol_fused(
    const float* __restrict__ x,
    const float* __restrict__ cw,
    const float* __restrict__ bng,
    const float* __restrict__ bnb,
    const float* __restrict__ bnm,
    const float* __restrict__ bnv,
    float* __restrict__ out)
{
    __shared__ float halo[GC_][HALO_H][HALO_W];   // 16*22*22*4 = 30976 B
    __shared__ float sscale[KK], sbias[KK];

    const int tid = threadIdx.x;
    const int tx = tid & 15;
    const int ty = tid >> 4;
    const int w0 = blockIdx.x * TW;
    const int h0 = blockIdx.y * TH;
    const int bz = blockIdx.z;           // b*G + g
    const int b  = bz >> 2;
    const int g  = bz & 3;
    const int h  = h0 + ty;
    const int w  = w0 + tx;

    // BN scale/bias for this group's 49 output channels
    if (tid < KK) {
        const int o = g * KK + tid;
        const float s = bng[o] * rsqrtf(bnv[o] + 1e-5f);
        sscale[tid] = s;
        sbias[tid]  = bnb[o] - bnm[o] * s;
    }

    // Stage the 16 group channels' halo tile (22x22) into LDS, zero-padded.
    const float* xg = x + ((size_t)(b * C_ + g * GC_)) * HW_;
    for (int i = tid; i < GC_ * HALO_H * HALO_W; i += 256) {
        const int c  = i / (HALO_H * HALO_W);
        const int r  = i - c * (HALO_H * HALO_W);
        const int hh = r / HALO_W;
        const int ww = r - hh * HALO_W;
        const int gh = h0 + hh - PAD;
        const int gw = w0 + ww - PAD;
        float v = 0.0f;
        if (gh >= 0 && gh < H_ && gw >= 0 && gw < W_)
            v = xg[c * HW_ + gh * W_ + gw];
        halo[c][hh][ww] = v;
    }

    // 1x1 conv: z[k] = sum_c x[b,c,h,w] * cw[g*49+k, c]
    // cw addresses are block-uniform -> compiler scalarizes to s_load (SMEM pipe).
    const float* __restrict__ cwg = cw + (size_t)g * KK * C_;
    const float* __restrict__ xc  = x + (size_t)b * C_ * HW_ + h * W_ + w;

    float z[KK];
#pragma unroll
    for (int k = 0; k < KK; ++k) z[k] = 0.0f;

    for (int c = 0; c < C_; ++c) {
        const float xv = xc[(size_t)c * HW_];
#pragma unroll
        for (int k = 0; k < KK; ++k)
            z[k] = fmaf(xv, cwg[k * C_ + c], z[k]);
    }

    __syncthreads();

    // BN (eval) + SiLU
#pragma unroll
    for (int k = 0; k < KK; ++k) {
        const float t = z[k] * sscale[k] + sbias[k];
        z[k] = t / (1.0f + expf(-t));
    }

    // Involution: out[b, g*16+c, h, w] = sum_k z[k] * halo[c][ty+kh][tx+kw]
    float* __restrict__ og = out + ((size_t)(b * C_ + g * GC_)) * HW_ + h * W_ + w;
#pragma unroll 4
    for (int c = 0; c < GC_; ++c) {
        float acc = 0.0f;
#pragma unroll
        for (int kh = 0; kh < KS; ++kh) {
#pragma unroll
            for (int kw = 0; kw < KS; ++kw) {
                acc = fmaf(z[kh * KS + kw], halo[c][ty + kh][tx + kw], acc);
            }
        }
        og[(size_t)c * HW_] = acc;
    }
}

extern "C" void kernel_launch(void* const* d_in, const int* in_sizes, int n_in,
                              void* d_out, int out_size, void* d_ws, size_t ws_size,
                              hipStream_t stream) {
    const float* x   = (const float*)d_in[0];
    const float* cw  = (const float*)d_in[1];
    const float* bng = (const float*)d_in[2];
    const float* bnb = (const float*)d_in[3];
    const float* bnm = (const float*)d_in[4];
    const float* bnv = (const float*)d_in[5];
    float* out = (float*)d_out;

    dim3 grid(W_ / TW, H_ / TH, B_ * G_);   // 8 x 8 x 16
    dim3 block(256);
    invol_fused<<<grid, block, 0, stream>>>(x, cw, bng, bnb, bnm, bnv, out);
}

// Round 2
// 70.237 us; speedup vs baseline: 1.0385x; 1.0385x over previous
//
#include <hip/hip_runtime.h>

#define B_   4
#define C_   64
#define H_   128
#define W_   128
#define KS   7
#define G_   4
#define GC_  16
#define KK   49
#define PAD  3
#define TH   16
#define TW   16
#define HW_  (H_ * W_)
#define HALO_H 22
#define HALO_W 22
#define HSTRIDE 23            // padded halo row stride (floats) — breaks bank pattern
#define ZSTRIDE 52            // z row stride (ushorts) = 104B, 8B-aligned rows

typedef float f32x4  __attribute__((ext_vector_type(4)));
typedef short bf16x8 __attribute__((ext_vector_type(8)));

__device__ __forceinline__ unsigned short f2bf(float f) {   // RNE float->bf16
    unsigned u = __float_as_uint(f);
    unsigned r = u + 0x7FFFu + ((u >> 16) & 1u);
    return (unsigned short)(r >> 16);
}

__global__ __launch_bounds__(256, 2) void invol_mfma(
    const float* __restrict__ x,
    const float* __restrict__ cw,
    const float* __restrict__ bng,
    const float* __restrict__ bnb,
    const float* __restrict__ bnm,
    const float* __restrict__ bnv,
    float* __restrict__ out)
{
    __shared__ float halo[GC_ * HALO_H * HSTRIDE];              // 32384 B
    __shared__ __align__(16) unsigned short z_sh[256 * ZSTRIDE]; // 26624 B
    __shared__ float sscale[KK], sbias[KK];

    const int tid  = threadIdx.x;
    const int lane = tid & 63;
    const int wv   = tid >> 6;        // wave 0..3
    const int l15  = lane & 15;
    const int l4   = lane >> 4;

    const int w0 = blockIdx.x * TW;
    const int h0 = blockIdx.y * TH;
    const int bz = blockIdx.z;        // b*G + g
    const int b  = bz >> 2;
    const int g  = bz & 3;

    // ---- BN constants for this group's 49 kernel channels ----
    if (tid < KK) {
        const int o = g * KK + tid;
        const float s = bng[o] * rsqrtf(bnv[o] + 1e-5f);
        sscale[tid] = s;
        sbias[tid]  = bnb[o] - bnm[o] * s;
    }

    // ---- stage halo (group's 16 channels, 22x22, zero-padded) ----
    const float* xg = x + (size_t)(b * C_ + g * GC_) * HW_;
    for (int i = tid; i < GC_ * HALO_H * HALO_W; i += 256) {
        const int c  = i / (HALO_H * HALO_W);
        const int r  = i - c * (HALO_H * HALO_W);
        const int hh = r / HALO_W;
        const int ww = r - hh * HALO_W;
        const int gh = h0 + hh - PAD;
        const int gw = w0 + ww - PAD;
        float v = 0.0f;
        if (gh >= 0 && gh < H_ && gw >= 0 && gw < W_)
            v = xg[c * HW_ + gh * W_ + gw];
        halo[c * (HALO_H * HSTRIDE) + hh * HSTRIDE + ww] = v;
    }

    // ---- A fragments: A[px][c] bf16, px = mtg*16 + l15, c = ks*32 + l4*8 + j ----
    // wave wv owns m-tiles mtg = wv*4 + mt  (image row h0 + mtg, col w0 + l15)
    bf16x8 afr[4][2];
    {
        const float* xb = x + (size_t)b * C_ * HW_;
#pragma unroll
        for (int mt = 0; mt < 4; ++mt) {
            const int hh = h0 + wv * 4 + mt;
            const float* xp = xb + hh * W_ + (w0 + l15);
#pragma unroll
            for (int ks = 0; ks < 2; ++ks) {
                const int c0 = ks * 32 + l4 * 8;
                bf16x8 a;
#pragma unroll
                for (int j = 0; j < 8; ++j)
                    a[j] = (short)f2bf(xp[(size_t)(c0 + j) * HW_]);
                afr[mt][ks] = a;
            }
        }
    }

    // ---- B fragments: B[c][k] bf16, k = nt*16 + l15 (zero if k>=49) ----
    bf16x8 bfr[4][2];
    {
#pragma unroll
        for (int nt = 0; nt < 4; ++nt) {
            const int kout = nt * 16 + l15;
            const bool kv = (kout < KK);
            const float* wp = cw + (size_t)(g * KK + (kv ? kout : 0)) * C_;
#pragma unroll
            for (int ks = 0; ks < 2; ++ks) {
                const int c0 = ks * 32 + l4 * 8;
                bf16x8 bb;
#pragma unroll
                for (int j = 0; j < 8; ++j)
                    bb[j] = kv ? (short)f2bf(wp[c0 + j]) : (short)0;
                bfr[nt][ks] = bb;
            }
        }
    }

    __syncthreads();   // halo + BN consts visible

    // ---- MFMA: z[px][k] = sum_c x*W ----
    f32x4 acc[4][4];
#pragma unroll
    for (int mt = 0; mt < 4; ++mt)
#pragma unroll
        for (int nt = 0; nt < 4; ++nt) {
            f32x4 a = {0.f, 0.f, 0.f, 0.f};
            a = __builtin_amdgcn_mfma_f32_16x16x32_bf16(afr[mt][0], bfr[nt][0], a, 0, 0, 0);
            a = __builtin_amdgcn_mfma_f32_16x16x32_bf16(afr[mt][1], bfr[nt][1], a, 0, 0, 0);
            acc[mt][nt] = a;
        }

    // ---- epilogue: BN + SiLU, write z to LDS (bf16) ----
    // D layout: col = lane&15 (k within n-tile), row16 = l4*4 + r (px within m-tile)
#pragma unroll
    for (int nt = 0; nt < 4; ++nt) {
        const int k = nt * 16 + l15;
        if (k < KK) {
            const float sc = sscale[k];
            const float bi = sbias[k];
#pragma unroll
            for (int mt = 0; mt < 4; ++mt) {
                const int px0 = (wv * 4 + mt) * 16 + l4 * 4;
#pragma unroll
                for (int r = 0; r < 4; ++r) {
                    const float t = acc[mt][nt][r] * sc + bi;
                    const float wgt = __fdividef(t, 1.0f + __expf(-t));
                    z_sh[(px0 + r) * ZSTRIDE + k] = f2bf(wgt);
                }
            }
        }
    }

    __syncthreads();   // z visible

    // ---- involution: thread owns pixel tid ----
    const int ty = tid >> 4;
    const int tx = tid & 15;

    float z49[KK];
    {
        const unsigned short* zr = &z_sh[tid * ZSTRIDE];
        const uint2* zp = reinterpret_cast<const uint2*>(zr);
#pragma unroll
        for (int j = 0; j < 12; ++j) {
            const uint2 q = zp[j];
            z49[4 * j + 0] = __uint_as_float(q.x << 16);
            z49[4 * j + 1] = __uint_as_float(q.x & 0xFFFF0000u);
            z49[4 * j + 2] = __uint_as_float(q.y << 16);
            z49[4 * j + 3] = __uint_as_float(q.y & 0xFFFF0000u);
        }
        z49[48] = __uint_as_float((unsigned)zr[48] << 16);
    }

    float* og = out + (size_t)(b * C_ + g * GC_) * HW_ + (h0 + ty) * W_ + (w0 + tx);
    const float* hbase = &halo[ty * HSTRIDE + tx];
#pragma unroll 4
    for (int c = 0; c < GC_; ++c) {
        const float* hp = hbase + c * (HALO_H * HSTRIDE);
        float a = 0.0f;
#pragma unroll
        for (int kh = 0; kh < KS; ++kh)
#pragma unroll
            for (int kw = 0; kw < KS; ++kw)
                a = fmaf(z49[kh * KS + kw], hp[kh * HSTRIDE + kw], a);
        og[(size_t)c * HW_] = a;
    }
}

extern "C" void kernel_launch(void* const* d_in, const int* in_sizes, int n_in,
                              void* d_out, int out_size, void* d_ws, size_t ws_size,
                              hipStream_t stream) {
    const float* x   = (const float*)d_in[0];
    const float* cw  = (const float*)d_in[1];
    const float* bng = (const float*)d_in[2];
    const float* bnb = (const float*)d_in[3];
    const float* bnm = (const float*)d_in[4];
    const float* bnv = (const float*)d_in[5];
    float* out = (float*)d_out;

    dim3 grid(W_ / TW, H_ / TH, B_ * G_);   // 8 x 8 x 16
    dim3 block(256);
    invol_mfma<<<grid, block, 0, stream>>>(x, cw, bng, bnb, bnm, bnv, out);
}